// Round 5
// baseline (1743.347 us; speedup 1.0000x reference)
//
#include <hip/hip_runtime.h>
#include <cfloat>
#include <stdint.h>

// Problem constants
#define NROWS   32768
#define NCODES  8192
#define KDIM    256
#define QOUT_OFFSET (NROWS * KDIM)

// Main-kernel tiling (16x16x32 MFMA, TLP-oriented)
#define BM      64              // rows per block
#define NQ      4               // codebook quarters
#define CODES_Q (NCODES / NQ)   // 2048
#define THREADS 512             // 8 waves; wave tile 64 rows x 32 codes

// Panel geometry (per 128-code, 32-k panel, 16x16 fragment order)
// Storage order [q][wp][ct][kc] -> each wave's B pointer walks +BBUF/iter.
#define BPAN 8192               // 128 codes * 32 k * 2 B, one split
#define BBUF (2 * BPAN)         // hi+lo 16384
#define ALDS_SPLIT 32768        // 64 rows * 256 k * 2 B per split
// LDS: 65536 B -> 2 blocks/CU (16 waves/CU with regs <= 128)

typedef __bf16 bf16x4 __attribute__((ext_vector_type(4)));
typedef __bf16 bf16x8 __attribute__((ext_vector_type(8)));
typedef float  f32x4  __attribute__((ext_vector_type(4)));

// ---------------------------------------------------------------------------
// K1: codebook -> hi/lo bf16 panels in 16x16-MFMA-fragment order, + cnorm.
// Panel storage index P = q*128 + wp*64 + ct*8 + kc  (wp = panel parity,
// ct = 256-code tile) so K2's per-wave walk over (ct,kc) is linear.
// Within panel: byte = (jj*64 + lanefrag)*16 + rem*2, jj = (code&127)>>4,
// lanefrag = ((k&31)>>3 <<4) | (code&15), rem = k&7.
// ---------------------------------------------------------------------------
__global__ void vq_panel_kernel(const float* __restrict__ cb,
                                char* __restrict__ cbP,
                                float* __restrict__ cnorm) {
    const int t    = threadIdx.x;
    const int row  = t >> 2;
    const int seg  = t & 3;
    const int code = blockIdx.x * 64 + row;
    const int cl   = code & 127;
    const int qq   = code >> 11;
    const int ptl  = (code >> 7) & 15;
    const int wp   = ptl & 1;
    const int ctp  = ptl >> 1;
    const float4* cb4 = (const float4*)cb;

    float ssq = 0.f;
    #pragma unroll
    for (int i = 0; i < 16; ++i) {
        int f = seg * 16 + i;            // float4 index in row, 0..63
        float4 v = cb4[(size_t)code * 64 + f];
        int k   = f * 4;
        int kc  = k >> 5;
        int kl  = k & 31;
        int oct = kl >> 3;
        int rem = kl & 7;                // 0 or 4
        bf16x4 h, l;
        float xs[4] = {v.x, v.y, v.z, v.w};
        #pragma unroll
        for (int e = 0; e < 4; ++e) {
            __bf16 hh = (__bf16)xs[e];
            h[e] = hh;
            l[e] = (__bf16)(xs[e] - (float)hh);
            ssq  = fmaf(xs[e], xs[e], ssq);
        }
        int lanefrag = (oct << 4) | (cl & 15);
        char* base = cbP + (size_t)(qq * 128 + wp * 64 + ctp * 8 + kc) * BBUF
                         + ((cl >> 4) * 64 + lanefrag) * 16 + rem * 2;
        *(bf16x4*)base          = h;
        *(bf16x4*)(base + BPAN) = l;
    }
    ssq += __shfl_xor(ssq, 1, 64);
    ssq += __shfl_xor(ssq, 2, 64);
    if (seg == 0) cnorm[code] = ssq;
}

// ---------------------------------------------------------------------------
// K2: split-bf16 16x16x32 MFMA distances + per-quarter argmin partials.
// 8 waves/block, wave tile 64 rows x 32 codes -> per-wave state ~120 unified
// regs -> 16 waves/CU (4/SIMD): latency hidden by TLP, not deep reg buffers
// (R2/R4 lesson: deep buffers spill; R3 lesson: 2 waves/SIMD can't cover).
// B pointer walks +BBUF linearly; A reads are ds_read with pure immediates.
// ---------------------------------------------------------------------------
__global__ __launch_bounds__(THREADS, 4) void vq_main_kernel(
        const float* __restrict__ z, const char* __restrict__ cbP,
        const float* __restrict__ cnorm,
        float* __restrict__ partD, int* __restrict__ partI) {

    __shared__ __align__(16) char Alds[2 * ALDS_SPLIT];   // 65536 B

    const int t     = threadIdx.x;
    const int wave  = t >> 6;
    const int lane  = t & 63;
    const int l15   = lane & 15;
    const int w3    = wave & 3;            // j-group pair within panel
    const int wp    = wave >> 2;           // panel parity half
    const int q     = blockIdx.x >> 9;
    const int row0  = (blockIdx.x & 511) * BM;
    const int qcode = q * CODES_Q;

    const float4* z4 = (const float4*)z;

    f32x4 acc[4][2];
    float mv[16];
    int   mi[16];
    #pragma unroll
    for (int i = 0; i < 4; ++i)
        #pragma unroll
        for (int j = 0; j < 2; ++j)
            acc[i][j] = (f32x4){0.f, 0.f, 0.f, 0.f};
    #pragma unroll
    for (int s = 0; s < 16; ++s) { mv[s] = FLT_MAX; mi[s] = 0; }

    // ---- prologue: stage A (all 8 kc, hi+lo, 16x16 fragment order) ----
    // slot = ((kc*4 + row16)*64 + (oct<<4) + row&15)*16 ; lo at +32768
    {
        const int arow = t >> 3;           // 0..63
        const int aseg = t & 7;            // 0..7 == kc
        #pragma unroll
        for (int p = 0; p < 4; ++p) {      // oct
            float4 f0 = z4[(size_t)(row0 + arow) * 64 + aseg * 8 + 2 * p];
            float4 f1 = z4[(size_t)(row0 + arow) * 64 + aseg * 8 + 2 * p + 1];
            float xs[8] = {f0.x, f0.y, f0.z, f0.w, f1.x, f1.y, f1.z, f1.w};
            bf16x8 hv, lv;
            #pragma unroll
            for (int e = 0; e < 8; ++e) {
                __bf16 hh = (__bf16)xs[e];
                hv[e] = hh;
                lv[e] = (__bf16)(xs[e] - (float)hh);
            }
            int slot = ((aseg * 4 + (arow >> 4)) * 64 + (p << 4) + (arow & 15)) * 16;
            *(bf16x8*)(Alds + slot)              = hv;
            *(bf16x8*)(Alds + ALDS_SPLIT + slot) = lv;
        }
    }

    // ---- prologue: B fragments for iter 0 (ct=0, kc=0) ----
    const char* pq = cbP + (size_t)(q * 128 + wp * 64) * BBUF
                         + w3 * 2048 + lane * 16;
    bf16x8 B0h[2], B0l[2], B1h[2], B1l[2];
    B0h[0] = *(const bf16x8*)(pq);
    B0h[1] = *(const bf16x8*)(pq + 1024);
    B0l[0] = *(const bf16x8*)(pq + BPAN);
    B0l[1] = *(const bf16x8*)(pq + BPAN + 1024);
    const char* pbh = pq + BBUF;
    const char* pbl = pq + BPAN + BBUF;

    __syncthreads();   // A ready; the ONLY barrier before the reduction

    const char* ab = (const char*)Alds + (lane << 4);

#define VQ_HALF(KC, IB, CH_, CL_)                                             \
    {                                                                         \
        bf16x8 ah[2], al[2];                                                  \
        _Pragma("unroll")                                                     \
        for (int ii = 0; ii < 2; ++ii) {                                      \
            ah[ii] = *(const bf16x8*)(ab + (KC) * 4096 + ((IB) + ii) * 1024); \
            al[ii] = *(const bf16x8*)(ab + ALDS_SPLIT + (KC) * 4096 + ((IB) + ii) * 1024); \
        }                                                                     \
        __builtin_amdgcn_s_setprio(1);                                        \
        _Pragma("unroll")                                                     \
        for (int ii = 0; ii < 2; ++ii)                                        \
            _Pragma("unroll")                                                 \
            for (int j = 0; j < 2; ++j)                                       \
                acc[(IB) + ii][j] = __builtin_amdgcn_mfma_f32_16x16x32_bf16(  \
                    ah[ii], CH_[j], acc[(IB) + ii][j], 0, 0, 0);              \
        _Pragma("unroll")                                                     \
        for (int ii = 0; ii < 2; ++ii)                                        \
            _Pragma("unroll")                                                 \
            for (int j = 0; j < 2; ++j)                                       \
                acc[(IB) + ii][j] = __builtin_amdgcn_mfma_f32_16x16x32_bf16(  \
                    ah[ii], CL_[j], acc[(IB) + ii][j], 0, 0, 0);              \
        _Pragma("unroll")                                                     \
        for (int ii = 0; ii < 2; ++ii)                                        \
            _Pragma("unroll")                                                 \
            for (int j = 0; j < 2; ++j)                                       \
                acc[(IB) + ii][j] = __builtin_amdgcn_mfma_f32_16x16x32_bf16(  \
                    al[ii], CH_[j], acc[(IB) + ii][j], 0, 0, 0);              \
        __builtin_amdgcn_s_setprio(0);                                        \
    }

#define VQ_IT(KC, CH_, CL_, NH_, NL_)                                         \
    {                                                                         \
        NH_[0] = *(const bf16x8*)(pbh);                                       \
        NH_[1] = *(const bf16x8*)(pbh + 1024);                                \
        NL_[0] = *(const bf16x8*)(pbl);                                       \
        NL_[1] = *(const bf16x8*)(pbl + 1024);                                \
        pbh += BBUF; pbl += BBUF;                                             \
        VQ_HALF(KC, 0, CH_, CL_)                                              \
        VQ_HALF(KC, 2, CH_, CL_)                                              \
    }

    for (int ct = 0; ct < 8; ++ct) {
        const int  cbase = qcode + (ct * 2 + wp) * 128 + w3 * 32 + l15;
        const float cn0  = cnorm[cbase];
        const float cn1  = cnorm[cbase + 16];

        VQ_IT(0, B0h, B0l, B1h, B1l)
        VQ_IT(1, B1h, B1l, B0h, B0l)
        VQ_IT(2, B0h, B0l, B1h, B1l)
        VQ_IT(3, B1h, B1l, B0h, B0l)
        VQ_IT(4, B0h, B0l, B1h, B1l)
        VQ_IT(5, B1h, B1l, B0h, B0l)
        VQ_IT(6, B0h, B0l, B1h, B1l)
        VQ_IT(7, B1h, B1l, B0h, B0l)
        // (final iter's prefetch overreads one panel past the quarter:
        //  lands in other panels / partD region -> valid memory, unused)

        // ---- epilogue: distances + argmin update, zero acc ----
        #pragma unroll
        for (int j = 0; j < 2; ++j) {
            const float cn   = j ? cn1 : cn0;
            const int   code = cbase + j * 16;
            #pragma unroll
            for (int i = 0; i < 4; ++i) {
                #pragma unroll
                for (int r = 0; r < 4; ++r) {
                    float d = fmaf(-2.f, acc[i][j][r], cn);
                    const int s = i * 4 + r;
                    if (d < mv[s]) { mv[s] = d; mi[s] = code; }
                }
            }
        }
        #pragma unroll
        for (int i = 0; i < 4; ++i)
            #pragma unroll
            for (int j = 0; j < 2; ++j)
                acc[i][j] = (f32x4){0.f, 0.f, 0.f, 0.f};
    }
#undef VQ_IT
#undef VQ_HALF

    // ---- reduction: 16-lane butterfly (codes), then cross-wave via LDS ----
    #pragma unroll
    for (int s = 0; s < 16; ++s) {
        #pragma unroll
        for (int m = 1; m <= 8; m <<= 1) {
            float ov = __shfl_xor(mv[s], m, 64);
            int   oi = __shfl_xor(mi[s], m, 64);
            if (ov < mv[s] || (ov == mv[s] && oi < mi[s])) { mv[s] = ov; mi[s] = oi; }
        }
    }
    __syncthreads();
    float* redV = (float*)Alds;                 // [8 wave][64 rows]
    int*   redI = (int*)(Alds + 8 * BM * 4);
    if (l15 == 0) {
        const int qq = lane >> 4;
        #pragma unroll
        for (int i = 0; i < 4; ++i)
            #pragma unroll
            for (int r = 0; r < 4; ++r) {
                int rowl = i * 16 + qq * 4 + r;
                redV[wave * BM + rowl] = mv[i * 4 + r];
                redI[wave * BM + rowl] = mi[i * 4 + r];
            }
    }
    __syncthreads();
    if (t < BM) {
        float bv = redV[t];
        int   bi = redI[t];
        #pragma unroll
        for (int w = 1; w < 8; ++w) {
            float v  = redV[w * BM + t];
            int   id = redI[w * BM + t];
            if (v < bv || (v == bv && id < bi)) { bv = v; bi = id; }
        }
        partD[(size_t)q * NROWS + row0 + t] = bv;
        partI[(size_t)q * NROWS + row0 + t] = bi;
    }
}

// ---------------------------------------------------------------------------
// K3: merge 4 quarter-partials per row -> final index (ascending q keeps
// numpy first-min tie-breaking).
// ---------------------------------------------------------------------------
__global__ void vq_merge_kernel(const float* __restrict__ partD,
                                const int* __restrict__ partI,
                                float* __restrict__ idx_out) {
    const int row = blockIdx.x * 256 + threadIdx.x;
    float bv = partD[row];
    int   bi = partI[row];
    #pragma unroll
    for (int q = 1; q < NQ; ++q) {
        float v  = partD[(size_t)q * NROWS + row];
        int   id = partI[(size_t)q * NROWS + row];
        if (v < bv || (v == bv && id < bi)) { bv = v; bi = id; }
    }
    idx_out[row] = (float)bi;
}

// ---------------------------------------------------------------------------
// K4: gather codebook rows into quantized output (bit-exact fp32).
// ---------------------------------------------------------------------------
__global__ void vq_gather_kernel(const float* __restrict__ cb,
                                 const float* __restrict__ idx_f,
                                 float* __restrict__ quant) {
    const int t   = threadIdx.x;
    const int row = blockIdx.x * 64 + (t >> 2);
    const int seg = t & 3;
    const int best = (int)idx_f[row];
    const float4* src = (const float4*)cb + (size_t)best * (KDIM / 4);
    float4* dst = (float4*)quant + (size_t)row * (KDIM / 4);
    #pragma unroll
    for (int i = 0; i < 16; ++i)
        dst[seg * 16 + i] = src[seg * 16 + i];
}

// ---------------------------------------------------------------------------
extern "C" void kernel_launch(void* const* d_in, const int* in_sizes, int n_in,
                              void* d_out, int out_size, void* d_ws, size_t ws_size,
                              hipStream_t stream) {
    const float* z  = (const float*)d_in[0];
    const float* cb = (const float*)d_in[1];
    float* quant   = (float*)d_out;
    float* idx_out = (float*)d_out + QOUT_OFFSET;
    float* cnorm   = (float*)d_ws;                 // 32 KB scratch
    char*  cbP     = (char*)d_out;                 // 8 MB panels in quant region
    float* partD   = (float*)((char*)d_out + 8 * 1024 * 1024);   // 512 KB
    int*   partI   = (int*)((char*)d_out + 8 * 1024 * 1024 + NQ * NROWS * 4);
    // panels+partials live inside the 32 MB quant region; K4 overwrites last

    vq_panel_kernel<<<NCODES / 64, 256, 0, stream>>>(cb, cbP, cnorm);
    vq_main_kernel<<<NQ * (NROWS / BM), THREADS, 0, stream>>>(z, cbP, cnorm, partD, partI);
    vq_merge_kernel<<<NROWS / 256, 256, 0, stream>>>(partD, partI, idx_out);
    vq_gather_kernel<<<NROWS / 64, 256, 0, stream>>>(cb, idx_out, quant);
}

// Round 6
// 836.427 us; speedup vs baseline: 2.0843x; 2.0843x over previous
//
#include <hip/hip_runtime.h>
#include <cfloat>
#include <stdint.h>

// Problem constants
#define NROWS   32768
#define NCODES  8192
#define KDIM    256
#define QOUT_OFFSET (NROWS * KDIM)

// Main-kernel tiling (16x16x32 MFMA, 3-waves/SIMD occupancy point)
#define BM      32              // rows per block
#define NQ      4               // codebook quarters
#define CODES_Q (NCODES / NQ)   // 2048
#define NKC     (KDIM / 32)     // 8
#define THREADS 256             // 4 waves; wave tile 32 rows x 64 codes

// Panel geometry (per 128-code panel, 16x16 fragment order, [pt][kc] linear)
#define BPAN 8192               // 128 codes * 32 k * 2 B, one split
#define BBUF (2 * BPAN)         // hi+lo 16384
#define ALDS_SPLIT 16384        // 32 rows * 256 k * 2 B per split
// LDS: 2 * 16384 = 32768 B -> 3 blocks/CU at (256,3) (96 KB of 160 KB)

typedef __bf16 bf16x4 __attribute__((ext_vector_type(4)));
typedef __bf16 bf16x8 __attribute__((ext_vector_type(8)));
typedef float  f32x4  __attribute__((ext_vector_type(4)));

// ---------------------------------------------------------------------------
// K1: codebook -> hi/lo bf16 panels in MFMA-fragment order, + cnorm.
// (verbatim from the 326 us round-1 kernel; [pt][kc]-linear panel order)
// ---------------------------------------------------------------------------
__global__ void vq_panel_kernel(const float* __restrict__ cb,
                                char* __restrict__ cbP,
                                float* __restrict__ cnorm) {
    const int t    = threadIdx.x;
    const int row  = t >> 2;
    const int seg  = t & 3;
    const int code = blockIdx.x * 64 + row;
    const int cl   = code & 127;
    const int pt   = code >> 7;
    const float4* cb4 = (const float4*)cb;

    float ssq = 0.f;
    #pragma unroll
    for (int i = 0; i < 16; ++i) {
        int f = seg * 16 + i;            // float4 index in row, 0..63
        float4 v = cb4[(size_t)code * 64 + f];
        int k   = f * 4;
        int kc  = k >> 5;
        int kl  = k & 31;
        int oct = kl >> 3;
        int rem = kl & 7;                // 0 or 4
        bf16x4 h, l;
        float xs[4] = {v.x, v.y, v.z, v.w};
        #pragma unroll
        for (int e = 0; e < 4; ++e) {
            __bf16 hh = (__bf16)xs[e];
            h[e] = hh;
            l[e] = (__bf16)(xs[e] - (float)hh);
            ssq  = fmaf(xs[e], xs[e], ssq);
        }
        int lanefrag = (oct << 4) | (cl & 15);
        char* base = cbP + ((size_t)(pt * NKC + kc)) * BBUF
                         + ((cl >> 4) * 64 + lanefrag) * 16 + rem * 2;
        *(bf16x4*)base          = h;
        *(bf16x4*)(base + BPAN) = l;
    }
    ssq += __shfl_xor(ssq, 1, 64);
    ssq += __shfl_xor(ssq, 2, 64);
    if (seg == 0) cnorm[code] = ssq;
}

// ---------------------------------------------------------------------------
// K2: split-bf16 16x16x32 MFMA distances + per-quarter argmin partials.
// BM=32, 4 waves, wave tile 32 rows x 64 codes. (256,3) -> 3 blocks/CU =
// 3 waves/SIMD; per-wave state ~113 VGPR + 32 AGPR = 145 <= 170 cap
// (R5 lesson: budget must fit the launch-bounds cap with headroom).
// 24 MFMAs/iter; B 1-deep register dbuf with LINEAR pointer walk
// (+BBUF/iter, +9*BBUF at panel-group wrap); A via one LDS base + imms.
// ---------------------------------------------------------------------------
__global__ __launch_bounds__(THREADS, 3) void vq_main_kernel(
        const float* __restrict__ z, const char* __restrict__ cbP,
        const float* __restrict__ cnorm,
        float* __restrict__ partD, int* __restrict__ partI) {

    __shared__ __align__(16) char Alds[2 * ALDS_SPLIT];   // 32768 B

    const int t     = threadIdx.x;
    const int wave  = t >> 6;
    const int lane  = t & 63;
    const int l15   = lane & 15;
    const int q     = blockIdx.x >> 10;
    const int row0  = (blockIdx.x & 1023) * BM;
    const int qcode = q * CODES_Q;

    const float4* z4 = (const float4*)z;

    f32x4 acc[2][4];                      // [i rows16][j codes16]
    float mv[8];
    int   mi[8];
    #pragma unroll
    for (int i = 0; i < 2; ++i)
        #pragma unroll
        for (int j = 0; j < 4; ++j)
            acc[i][j] = (f32x4){0.f, 0.f, 0.f, 0.f};
    #pragma unroll
    for (int s = 0; s < 8; ++s) { mv[s] = FLT_MAX; mi[s] = 0; }

    // ---- prologue: stage A (32 rows, all 8 kc, hi+lo, fragment order) ----
    // slot = ((kc*2 + row16)*64 + (oct<<4) + (row&15))*16 ; lo at +16384
    {
        const int arow = t >> 3;           // 0..31
        const int aseg = t & 7;            // 0..7 == kc
        #pragma unroll
        for (int p = 0; p < 4; ++p) {      // oct
            float4 f0 = z4[(size_t)(row0 + arow) * 64 + aseg * 8 + 2 * p];
            float4 f1 = z4[(size_t)(row0 + arow) * 64 + aseg * 8 + 2 * p + 1];
            float xs[8] = {f0.x, f0.y, f0.z, f0.w, f1.x, f1.y, f1.z, f1.w};
            bf16x8 hv, lv;
            #pragma unroll
            for (int e = 0; e < 8; ++e) {
                __bf16 hh = (__bf16)xs[e];
                hv[e] = hh;
                lv[e] = (__bf16)(xs[e] - (float)hh);
            }
            int slot = ((aseg * 2 + (arow >> 4)) * 64 + (p << 4) + (arow & 15)) * 16;
            *(bf16x8*)(Alds + slot)              = hv;
            *(bf16x8*)(Alds + ALDS_SPLIT + slot) = lv;
        }
    }

    // ---- prologue: B fragments for (ct=0, kc=0) ----
    // wave w covers codes ct*256 + w*64 .. +63: panel pt = ct*2 + (w>>1),
    // within-panel j-group base (w&1)*4096. Panels are [pt][kc]-linear.
    const char* pbh = cbP + (size_t)(q * 128 + (wave >> 1) * 8) * BBUF
                          + (wave & 1) * 4096 + lane * 16;
    const char* pbl = pbh + BPAN;
    bf16x8 B0h[4], B0l[4], B1h[4], B1l[4];
    #pragma unroll
    for (int j = 0; j < 4; ++j) {
        B0h[j] = *(const bf16x8*)(pbh + j * 1024);
        B0l[j] = *(const bf16x8*)(pbl + j * 1024);
    }
    pbh += BBUF; pbl += BBUF;              // now points at (ct=0, kc=1)

    __syncthreads();   // A ready; the ONLY barrier before the reduction

    const char* ab = (const char*)Alds + (lane << 4);

// VQ_IT(KC): consume C* for kc=KC, prefetch the panel at pbh into N*,
// advance pbh/pbl by INC (9*BBUF at the kc==6 slot: (ct,7)->(ct+1,0)).
#define VQ_IT(KC, INC, CH_, CL_, NH_, NL_)                                    \
    {                                                                         \
        _Pragma("unroll")                                                     \
        for (int j = 0; j < 4; ++j) {                                         \
            NH_[j] = *(const bf16x8*)(pbh + j * 1024);                        \
            NL_[j] = *(const bf16x8*)(pbl + j * 1024);                        \
        }                                                                     \
        pbh += (INC); pbl += (INC);                                           \
        bf16x8 ah[2], al[2];                                                  \
        _Pragma("unroll")                                                     \
        for (int i = 0; i < 2; ++i) {                                         \
            ah[i] = *(const bf16x8*)(ab + (KC) * 2048 + i * 1024);            \
            al[i] = *(const bf16x8*)(ab + ALDS_SPLIT + (KC) * 2048 + i * 1024); \
        }                                                                     \
        __builtin_amdgcn_s_setprio(1);                                        \
        _Pragma("unroll")                                                     \
        for (int i = 0; i < 2; ++i)                                           \
            _Pragma("unroll")                                                 \
            for (int j = 0; j < 4; ++j)                                       \
                acc[i][j] = __builtin_amdgcn_mfma_f32_16x16x32_bf16(          \
                    ah[i], CH_[j], acc[i][j], 0, 0, 0);                       \
        _Pragma("unroll")                                                     \
        for (int i = 0; i < 2; ++i)                                           \
            _Pragma("unroll")                                                 \
            for (int j = 0; j < 4; ++j)                                       \
                acc[i][j] = __builtin_amdgcn_mfma_f32_16x16x32_bf16(          \
                    ah[i], CL_[j], acc[i][j], 0, 0, 0);                       \
        _Pragma("unroll")                                                     \
        for (int i = 0; i < 2; ++i)                                           \
            _Pragma("unroll")                                                 \
            for (int j = 0; j < 4; ++j)                                       \
                acc[i][j] = __builtin_amdgcn_mfma_f32_16x16x32_bf16(          \
                    al[i], CH_[j], acc[i][j], 0, 0, 0);                       \
        __builtin_amdgcn_s_setprio(0);                                        \
    }

    for (int ct = 0; ct < 8; ++ct) {
        const int  cbase = qcode + ct * 256 + wave * 64 + l15;
        float cnj[4];
        #pragma unroll
        for (int j = 0; j < 4; ++j)
            cnj[j] = cnorm[cbase + j * 16];   // used 8 iters later: hidden

        VQ_IT(0, BBUF,     B0h, B0l, B1h, B1l)
        VQ_IT(1, BBUF,     B1h, B1l, B0h, B0l)
        VQ_IT(2, BBUF,     B0h, B0l, B1h, B1l)
        VQ_IT(3, BBUF,     B1h, B1l, B0h, B0l)
        VQ_IT(4, BBUF,     B0h, B0l, B1h, B1l)
        VQ_IT(5, BBUF,     B1h, B1l, B0h, B0l)
        VQ_IT(6, 9 * BBUF, B0h, B0l, B1h, B1l)   // ptr jumps (ct,7)->(ct+1,0)
        VQ_IT(7, BBUF,     B1h, B1l, B0h, B0l)
        // (final ct's last prefetch overreads past the quarter's panels:
        //  lands in other panels / partD region -> valid memory, unused)

        // ---- epilogue: distances + argmin update, zero acc ----
        #pragma unroll
        for (int j = 0; j < 4; ++j) {            // ascending code: ties OK
            const float cn   = cnj[j];
            const int   code = cbase + j * 16;
            #pragma unroll
            for (int i = 0; i < 2; ++i)
                #pragma unroll
                for (int r = 0; r < 4; ++r) {
                    float d = fmaf(-2.f, acc[i][j][r], cn);
                    const int s = i * 4 + r;
                    if (d < mv[s]) { mv[s] = d; mi[s] = code; }
                }
        }
        #pragma unroll
        for (int i = 0; i < 2; ++i)
            #pragma unroll
            for (int j = 0; j < 4; ++j)
                acc[i][j] = (f32x4){0.f, 0.f, 0.f, 0.f};
    }
#undef VQ_IT

    // ---- reduction: 16-lane butterfly (codes), then cross-wave via LDS ----
    #pragma unroll
    for (int s = 0; s < 8; ++s) {
        #pragma unroll
        for (int m = 1; m <= 8; m <<= 1) {
            float ov = __shfl_xor(mv[s], m, 64);
            int   oi = __shfl_xor(mi[s], m, 64);
            if (ov < mv[s] || (ov == mv[s] && oi < mi[s])) { mv[s] = ov; mi[s] = oi; }
        }
    }
    __syncthreads();
    float* redV = (float*)Alds;                 // [4 wave][32 rows]
    int*   redI = (int*)(Alds + 4 * BM * 4);
    if (l15 == 0) {
        const int qq = lane >> 4;
        #pragma unroll
        for (int i = 0; i < 2; ++i)
            #pragma unroll
            for (int r = 0; r < 4; ++r) {
                int rowl = i * 16 + qq * 4 + r;
                redV[wave * BM + rowl] = mv[i * 4 + r];
                redI[wave * BM + rowl] = mi[i * 4 + r];
            }
    }
    __syncthreads();
    if (t < BM) {
        float bv = redV[t];
        int   bi = redI[t];
        #pragma unroll
        for (int w = 1; w < 4; ++w) {            // ascending wave = asc code
            float v  = redV[w * BM + t];
            int   id = redI[w * BM + t];
            if (v < bv || (v == bv && id < bi)) { bv = v; bi = id; }
        }
        partD[(size_t)q * NROWS + row0 + t] = bv;
        partI[(size_t)q * NROWS + row0 + t] = bi;
    }
}

// ---------------------------------------------------------------------------
// K3: merge 4 quarter-partials per row -> final index (ascending q keeps
// numpy first-min tie-breaking).
// ---------------------------------------------------------------------------
__global__ void vq_merge_kernel(const float* __restrict__ partD,
                                const int* __restrict__ partI,
                                float* __restrict__ idx_out) {
    const int row = blockIdx.x * 256 + threadIdx.x;
    float bv = partD[row];
    int   bi = partI[row];
    #pragma unroll
    for (int q = 1; q < NQ; ++q) {
        float v  = partD[(size_t)q * NROWS + row];
        int   id = partI[(size_t)q * NROWS + row];
        if (v < bv || (v == bv && id < bi)) { bv = v; bi = id; }
    }
    idx_out[row] = (float)bi;
}

// ---------------------------------------------------------------------------
// K4: gather codebook rows into quantized output (bit-exact fp32).
// ---------------------------------------------------------------------------
__global__ void vq_gather_kernel(const float* __restrict__ cb,
                                 const float* __restrict__ idx_f,
                                 float* __restrict__ quant) {
    const int t   = threadIdx.x;
    const int row = blockIdx.x * 64 + (t >> 2);
    const int seg = t & 3;
    const int best = (int)idx_f[row];
    const float4* src = (const float4*)cb + (size_t)best * (KDIM / 4);
    float4* dst = (float4*)quant + (size_t)row * (KDIM / 4);
    #pragma unroll
    for (int i = 0; i < 16; ++i)
        dst[seg * 16 + i] = src[seg * 16 + i];
}

// ---------------------------------------------------------------------------
extern "C" void kernel_launch(void* const* d_in, const int* in_sizes, int n_in,
                              void* d_out, int out_size, void* d_ws, size_t ws_size,
                              hipStream_t stream) {
    const float* z  = (const float*)d_in[0];
    const float* cb = (const float*)d_in[1];
    float* quant   = (float*)d_out;
    float* idx_out = (float*)d_out + QOUT_OFFSET;
    float* cnorm   = (float*)d_ws;                 // 32 KB scratch
    char*  cbP     = (char*)d_out;                 // 8 MB panels in quant region
    float* partD   = (float*)((char*)d_out + 8 * 1024 * 1024);   // 512 KB
    int*   partI   = (int*)((char*)d_out + 8 * 1024 * 1024 + NQ * NROWS * 4);
    // panels+partials live inside the 32 MB quant region; K4 overwrites last

    vq_panel_kernel<<<NCODES / 64, 256, 0, stream>>>(cb, cbP, cnorm);
    vq_main_kernel<<<NQ * (NROWS / BM), THREADS, 0, stream>>>(z, cbP, cnorm, partD, partI);
    vq_merge_kernel<<<NROWS / 256, 256, 0, stream>>>(partD, partI, idx_out);
    vq_gather_kernel<<<NROWS / 64, 256, 0, stream>>>(cb, idx_out, quant);
}

// Round 7
// 414.751 us; speedup vs baseline: 4.2034x; 2.0167x over previous
//
#include <hip/hip_runtime.h>
#include <cfloat>
#include <stdint.h>

// Problem constants
#define NROWS   32768
#define NCODES  8192
#define KDIM    256
#define QOUT_OFFSET (NROWS * KDIM)

// Main-kernel tiling (R1 champion structure, full-codebook scan)
#define BM      64              // rows per block
#define BN      256             // codes per block-tile (4 waves x 64)
#define NKC     (KDIM / 32)     // 8
#define NIT     (NCODES / BN * NKC)    // 32 ct * 8 kc = 256
#define THREADS 256             // 4 waves

// Fragment-order panel geometry (per 128-code panel), [pt][kc]-linear
#define BPAN 8192               // 128 codes * 32 k * 2 B, one split
#define BBUF (2 * BPAN)         // hi+lo 16384
#define ALDS_SPLIT 32768        // 64 rows * 256 k * 2 B per split
// LDS: 2 * 32768 = 65536 B -> 2 blocks/CU

typedef __bf16 bf16x4 __attribute__((ext_vector_type(4)));
typedef __bf16 bf16x8 __attribute__((ext_vector_type(8)));
typedef float  f32x4  __attribute__((ext_vector_type(4)));

// ---------------------------------------------------------------------------
// K1: codebook -> hi/lo bf16 panels in MFMA-fragment order, + cnorm.
// (verbatim from the 327 us champion; refcheck-clean)
// ---------------------------------------------------------------------------
__global__ void vq_panel_kernel(const float* __restrict__ cb,
                                char* __restrict__ cbP,
                                float* __restrict__ cnorm) {
    const int t    = threadIdx.x;
    const int row  = t >> 2;
    const int seg  = t & 3;
    const int code = blockIdx.x * 64 + row;
    const int cl   = code & 127;
    const int pt   = code >> 7;
    const float4* cb4 = (const float4*)cb;

    float ssq = 0.f;
    #pragma unroll
    for (int i = 0; i < 16; ++i) {
        int f = seg * 16 + i;            // float4 index in row, 0..63
        float4 v = cb4[(size_t)code * 64 + f];
        int k   = f * 4;
        int kc  = k >> 5;
        int kl  = k & 31;
        int oct = kl >> 3;
        int rem = kl & 7;                // 0 or 4
        bf16x4 h, l;
        float xs[4] = {v.x, v.y, v.z, v.w};
        #pragma unroll
        for (int e = 0; e < 4; ++e) {
            __bf16 hh = (__bf16)xs[e];
            h[e] = hh;
            l[e] = (__bf16)(xs[e] - (float)hh);
            ssq  = fmaf(xs[e], xs[e], ssq);
        }
        int lanefrag = (oct << 4) | (cl & 15);
        char* base = cbP + ((size_t)(pt * NKC + kc)) * BBUF
                         + ((cl >> 4) * 64 + lanefrag) * 16 + rem * 2;
        *(bf16x4*)base          = h;
        *(bf16x4*)(base + BPAN) = l;
    }
    ssq += __shfl_xor(ssq, 1, 64);
    ssq += __shfl_xor(ssq, 2, 64);
    if (seg == 0) cnorm[code] = ssq;
}

// ---------------------------------------------------------------------------
// K2: split-bf16 MFMA distances + FULL-codebook argmin per row.
// R1 champion structure (VGPR 128, no spill, MfmaUtil 61%): barrier-free
// K-loop, A (z hi/lo) staged in LDS once, A+B 1-deep register dbuf,
// strength-reduced addressing, setprio around MFMA cluster. NEW: no quarter
// split (NIT=256, grid 512 = 2 blocks/CU exactly) -> z read once (was x4),
// no partials, final index written directly (K3 deleted).
// ---------------------------------------------------------------------------
__global__ __launch_bounds__(THREADS, 2) void vq_main_kernel(
        const float* __restrict__ z, const char* __restrict__ cbP,
        const float* __restrict__ cnorm,
        float* __restrict__ idx_out) {

    __shared__ __align__(16) char Alds[2 * ALDS_SPLIT];   // 65536 B

    const int t     = threadIdx.x;
    const int wave  = t >> 6;
    const int lane  = t & 63;
    const int l15   = lane & 15;
    const int row0  = blockIdx.x * BM;
    const int wp    = wave >> 1;           // wave's panel sub-group
    const int bvoff = ((wave & 1) * 256 + lane) * 16;   // lane part of B addr

    const float4* z4 = (const float4*)z;

    f32x4 acc[4][4];
    float mv[16];
    int   mi[16];
    #pragma unroll
    for (int i = 0; i < 4; ++i)
        #pragma unroll
        for (int j = 0; j < 4; ++j)
            acc[i][j] = (f32x4){0.f, 0.f, 0.f, 0.f};
    #pragma unroll
    for (int s = 0; s < 16; ++s) { mv[s] = FLT_MAX; mi[s] = 0; }

    // ---- prologue: stage A (all 8 kc, hi+lo, fragment order) ----
    {
        const int arow = t >> 2;
        const int aseg = t & 3;
        #pragma unroll
        for (int p = 0; p < 8; ++p) {
            float4 f0 = z4[(size_t)(row0 + arow) * 64 + aseg * 16 + 2 * p];
            float4 f1 = z4[(size_t)(row0 + arow) * 64 + aseg * 16 + 2 * p + 1];
            float xs[8] = {f0.x, f0.y, f0.z, f0.w, f1.x, f1.y, f1.z, f1.w};
            bf16x8 hv, lv;
            #pragma unroll
            for (int e = 0; e < 8; ++e) {
                __bf16 hh = (__bf16)xs[e];
                hv[e] = hh;
                lv[e] = (__bf16)(xs[e] - (float)hh);
            }
            int kc  = aseg * 2 + (p >> 2);
            int oct = p & 3;
            int slot = ((kc * 4 + (arow >> 4)) * 64 + (oct << 4) + (arow & 15)) * 16;
            *(bf16x8*)(Alds + slot)              = hv;
            *(bf16x8*)(Alds + ALDS_SPLIT + slot) = lv;
        }
    }

    // ---- prologue: B fragments for iter 0 (ct=0, kc=0) ----
    bf16x8 B0h[4], B0l[4], B1h[4], B1l[4];
    {
        const char* pb  = cbP + ((size_t)wp * 8) * BBUF + bvoff;
        const char* pbl = pb + BPAN;
        #pragma unroll
        for (int j = 0; j < 4; ++j) {
            B0h[j] = *(const bf16x8*)(pb  + j * 1024);
            B0l[j] = *(const bf16x8*)(pbl + j * 1024);
        }
    }

    __syncthreads();   // A ready; the ONLY barrier before the reduction

    // ---- prologue: A fragments for iter 0 (kc=0) ----
    bf16x8 A0h[4], A0l[4], A1h[4], A1l[4];
    {
        const char* ab = Alds + (lane << 4);
        #pragma unroll
        for (int i = 0; i < 4; ++i) {
            A0h[i] = *(const bf16x8*)(ab + i * 1024);
            A0l[i] = *(const bf16x8*)(ab + ALDS_SPLIT + i * 1024);
        }
    }

    float cnj[4];

#define VQ_BODY(N, CAH, CAL, NAH, NAL, CBH, CBL, NBH, NBL)                    \
    {                                                                         \
        const int ct = (N) >> 3, kc = (N) & 7;                                \
        const int np = (N) + 1;                                               \
        if (np < NIT) {                                                       \
            const int ct1 = np >> 3, kc1 = np & 7;                            \
            const char* pb  = cbP                                             \
                + ((size_t)((ct1 * 2 + wp) * 8 + kc1)) * BBUF + bvoff;        \
            const char* pbl = pb + BPAN;                                      \
            _Pragma("unroll")                                                 \
            for (int j = 0; j < 4; ++j) {                                     \
                NBH[j] = *(const bf16x8*)(pb  + j * 1024);                    \
                NBL[j] = *(const bf16x8*)(pbl + j * 1024);                    \
            }                                                                 \
        }                                                                     \
        {                                                                     \
            const int kcn = np & 7;                                           \
            const char* ab = Alds + (kcn << 12) + (lane << 4);                \
            _Pragma("unroll")                                                 \
            for (int i = 0; i < 4; ++i) {                                     \
                NAH[i] = *(const bf16x8*)(ab + i * 1024);                     \
                NAL[i] = *(const bf16x8*)(ab + ALDS_SPLIT + i * 1024);        \
            }                                                                 \
        }                                                                     \
        if (kc == 0) {                                                        \
            _Pragma("unroll")                                                 \
            for (int j = 0; j < 4; ++j)                                       \
                cnj[j] = cnorm[(ct * 16 + wave * 4 + j) * 16 + l15];          \
        }                                                                     \
        __builtin_amdgcn_s_setprio(1);                                        \
        _Pragma("unroll")                                                     \
        for (int i = 0; i < 4; ++i)                                           \
            _Pragma("unroll")                                                 \
            for (int j = 0; j < 4; ++j)                                       \
                acc[i][j] = __builtin_amdgcn_mfma_f32_16x16x32_bf16(          \
                                CAH[i], CBH[j], acc[i][j], 0, 0, 0);          \
        _Pragma("unroll")                                                     \
        for (int i = 0; i < 4; ++i)                                           \
            _Pragma("unroll")                                                 \
            for (int j = 0; j < 4; ++j)                                       \
                acc[i][j] = __builtin_amdgcn_mfma_f32_16x16x32_bf16(          \
                                CAH[i], CBL[j], acc[i][j], 0, 0, 0);          \
        _Pragma("unroll")                                                     \
        for (int i = 0; i < 4; ++i)                                           \
            _Pragma("unroll")                                                 \
            for (int j = 0; j < 4; ++j)                                       \
                acc[i][j] = __builtin_amdgcn_mfma_f32_16x16x32_bf16(          \
                                CAL[i], CBH[j], acc[i][j], 0, 0, 0);          \
        __builtin_amdgcn_s_setprio(0);                                        \
        if (kc == 7) {                                                        \
            _Pragma("unroll")                                                 \
            for (int j = 0; j < 4; ++j) {                                     \
                int code = (ct * 16 + wave * 4 + j) * 16 + l15;               \
                float cn = cnj[j];                                            \
                _Pragma("unroll")                                             \
                for (int i = 0; i < 4; ++i) {                                 \
                    _Pragma("unroll")                                         \
                    for (int r = 0; r < 4; ++r) {                             \
                        float d = fmaf(-2.f, acc[i][j][r], cn);               \
                        int s = i * 4 + r;                                    \
                        if (d < mv[s]) { mv[s] = d; mi[s] = code; }           \
                    }                                                         \
                    acc[i][j] = (f32x4){0.f, 0.f, 0.f, 0.f};                  \
                }                                                             \
            }                                                                 \
        }                                                                     \
    }

    for (int n = 0; n < NIT; n += 2) {
        VQ_BODY(n,     A0h, A0l, A1h, A1l, B0h, B0l, B1h, B1l)
        VQ_BODY(n + 1, A1h, A1l, A0h, A0l, B1h, B1l, B0h, B0l)
    }
#undef VQ_BODY

    // ---- reduction: 16-lane butterfly (codes), then cross-wave via LDS ----
    // (index comparisons are on absolute code values -> exact numpy
    //  first-min tie-breaking regardless of wave/lane order)
    #pragma unroll
    for (int s = 0; s < 16; ++s) {
        #pragma unroll
        for (int m = 1; m <= 8; m <<= 1) {
            float ov = __shfl_xor(mv[s], m, 64);
            int   oi = __shfl_xor(mi[s], m, 64);
            if (ov < mv[s] || (ov == mv[s] && oi < mi[s])) { mv[s] = ov; mi[s] = oi; }
        }
    }
    __syncthreads();
    float* redV = (float*)Alds;                 // [4 wave][64 rows]
    int*   redI = (int*)(Alds + 4 * BM * 4);
    if (l15 == 0) {
        int qq = lane >> 4;
        #pragma unroll
        for (int i = 0; i < 4; ++i)
            #pragma unroll
            for (int r = 0; r < 4; ++r) {
                int ml = i * 16 + qq * 4 + r;
                redV[wave * BM + ml] = mv[i * 4 + r];
                redI[wave * BM + ml] = mi[i * 4 + r];
            }
    }
    __syncthreads();
    if (t < BM) {
        float bv = redV[t];
        int   bi = redI[t];
        #pragma unroll
        for (int w = 1; w < 4; ++w) {
            float v  = redV[w * BM + t];
            int   id = redI[w * BM + t];
            if (v < bv || (v == bv && id < bi)) { bv = v; bi = id; }
        }
        idx_out[row0 + t] = (float)bi;
    }
}

// ---------------------------------------------------------------------------
// K4: gather codebook rows into quantized output (bit-exact fp32).
// Runs after K2 completes -> free to overwrite the panel region of d_out.
// ---------------------------------------------------------------------------
__global__ void vq_gather_kernel(const float* __restrict__ cb,
                                 const float* __restrict__ idx_f,
                                 float* __restrict__ quant) {
    const int t   = threadIdx.x;
    const int row = blockIdx.x * 64 + (t >> 2);
    const int seg = t & 3;
    const int best = (int)idx_f[row];
    const float4* src = (const float4*)cb + (size_t)best * (KDIM / 4);
    float4* dst = (float4*)quant + (size_t)row * (KDIM / 4);
    #pragma unroll
    for (int i = 0; i < 16; ++i)
        dst[seg * 16 + i] = src[seg * 16 + i];
}

// ---------------------------------------------------------------------------
extern "C" void kernel_launch(void* const* d_in, const int* in_sizes, int n_in,
                              void* d_out, int out_size, void* d_ws, size_t ws_size,
                              hipStream_t stream) {
    const float* z  = (const float*)d_in[0];
    const float* cb = (const float*)d_in[1];
    float* quant   = (float*)d_out;
    float* idx_out = (float*)d_out + QOUT_OFFSET;
    float* cnorm   = (float*)d_ws;                 // 32 KB scratch
    char*  cbP     = (char*)d_out;                 // 8 MB panels in quant region
    // panels live inside the 32 MB quant region; K4 overwrites them last

    vq_panel_kernel<<<NCODES / 64, 256, 0, stream>>>(cb, cbP, cnorm);
    vq_main_kernel<<<NROWS / BM, THREADS, 0, stream>>>(z, cbP, cnorm, idx_out);
    vq_gather_kernel<<<NROWS / 64, 256, 0, stream>>>(cb, idx_out, quant);
}

// Round 8
// 404.158 us; speedup vs baseline: 4.3135x; 1.0262x over previous
//
#include <hip/hip_runtime.h>
#include <cfloat>
#include <stdint.h>

// Problem constants
#define NROWS   32768
#define NCODES  8192
#define KDIM    256
#define QOUT_OFFSET (NROWS * KDIM)

// Main-kernel tiling (champion structure, full-codebook scan)
#define BM      64              // rows per block
#define BN      256             // codes per block-tile (4 waves x 64)
#define NKC     (KDIM / 32)     // 8
#define NIT     (NCODES / BN * NKC)    // 32 ct * 8 kc = 256
#define THREADS 256             // 4 waves

// Fragment-order panel geometry (per 128-code panel), [pt][kc]-linear
#define BPAN 8192               // 128 codes * 32 k * 2 B, one split
#define BBUF (2 * BPAN)         // hi+lo 16384
#define PANEL_BYTES (8u * 1024 * 1024)
#define ALDS_SPLIT 32768        // 64 rows * 256 k * 2 B per split
// LDS: 2 * 32768 = 65536 B -> 2 blocks/CU

typedef __bf16 bf16x4 __attribute__((ext_vector_type(4)));
typedef __bf16 bf16x8 __attribute__((ext_vector_type(8)));
typedef float  f32x4  __attribute__((ext_vector_type(4)));

// ---------------------------------------------------------------------------
// K1: codebook -> hi/lo bf16 panels in MFMA-fragment order, + cnorm.
// NEW: i-iterations paired (f, f+1 share kc/oct; rem 0 then 4) so each
// hi/lo panel write is one contiguous 16-B bf16x8 store (was 2x 8-B
// scattered) -> half the stores, full coalescing width. Byte layout
// produced is identical to the champion's.
// ---------------------------------------------------------------------------
__global__ void vq_panel_kernel(const float* __restrict__ cb,
                                char* __restrict__ cbP,
                                float* __restrict__ cnorm) {
    const int t    = threadIdx.x;
    const int row  = t >> 2;
    const int seg  = t & 3;
    const int code = blockIdx.x * 64 + row;
    const int cl   = code & 127;
    const int pt   = code >> 7;
    const float4* cb4 = (const float4*)cb;

    float ssq = 0.f;
    #pragma unroll
    for (int i2 = 0; i2 < 8; ++i2) {
        int f = seg * 16 + i2 * 2;       // even float4 index, 0..62
        float4 v0 = cb4[(size_t)code * 64 + f];
        float4 v1 = cb4[(size_t)code * 64 + f + 1];
        int k   = f * 4;                 // k ... k+7 covered by this pair
        int kc  = k >> 5;
        int oct = (k & 31) >> 3;
        float xs[8] = {v0.x, v0.y, v0.z, v0.w, v1.x, v1.y, v1.z, v1.w};
        bf16x8 h, l;
        #pragma unroll
        for (int e = 0; e < 8; ++e) {
            __bf16 hh = (__bf16)xs[e];
            h[e] = hh;
            l[e] = (__bf16)(xs[e] - (float)hh);
            ssq  = fmaf(xs[e], xs[e], ssq);
        }
        int lanefrag = (oct << 4) | (cl & 15);
        char* base = cbP + ((size_t)(pt * NKC + kc)) * BBUF
                         + ((cl >> 4) * 64 + lanefrag) * 16;
        *(bf16x8*)base          = h;
        *(bf16x8*)(base + BPAN) = l;
    }
    ssq += __shfl_xor(ssq, 1, 64);
    ssq += __shfl_xor(ssq, 2, 64);
    if (seg == 0) cnorm[code] = ssq;
}

// ---------------------------------------------------------------------------
// K2: split-bf16 MFMA distances + FULL-codebook argmin per row.
// Champion hot loop (VGPR 128, no spill, MfmaUtil 60%) byte-identical.
// FUSE=1 (panels in d_ws -> quant region unaliased): each block gathers its
// own 64 codebook rows into quant in the tail, eliminating K4 + one launch.
// ---------------------------------------------------------------------------
template <int FUSE>
__global__ __launch_bounds__(THREADS, 2) void vq_main_kernel(
        const float* __restrict__ z, const char* __restrict__ cbP,
        const float* __restrict__ cnorm, const float* __restrict__ cb,
        float* __restrict__ quant, float* __restrict__ idx_out) {

    __shared__ __align__(16) char Alds[2 * ALDS_SPLIT];   // 65536 B

    const int t     = threadIdx.x;
    const int wave  = t >> 6;
    const int lane  = t & 63;
    const int l15   = lane & 15;
    const int row0  = blockIdx.x * BM;
    const int wp    = wave >> 1;           // wave's panel sub-group
    const int bvoff = ((wave & 1) * 256 + lane) * 16;   // lane part of B addr

    const float4* z4 = (const float4*)z;

    f32x4 acc[4][4];
    float mv[16];
    int   mi[16];
    #pragma unroll
    for (int i = 0; i < 4; ++i)
        #pragma unroll
        for (int j = 0; j < 4; ++j)
            acc[i][j] = (f32x4){0.f, 0.f, 0.f, 0.f};
    #pragma unroll
    for (int s = 0; s < 16; ++s) { mv[s] = FLT_MAX; mi[s] = 0; }

    // ---- prologue: stage A (all 8 kc, hi+lo, fragment order) ----
    {
        const int arow = t >> 2;
        const int aseg = t & 3;
        #pragma unroll
        for (int p = 0; p < 8; ++p) {
            float4 f0 = z4[(size_t)(row0 + arow) * 64 + aseg * 16 + 2 * p];
            float4 f1 = z4[(size_t)(row0 + arow) * 64 + aseg * 16 + 2 * p + 1];
            float xs[8] = {f0.x, f0.y, f0.z, f0.w, f1.x, f1.y, f1.z, f1.w};
            bf16x8 hv, lv;
            #pragma unroll
            for (int e = 0; e < 8; ++e) {
                __bf16 hh = (__bf16)xs[e];
                hv[e] = hh;
                lv[e] = (__bf16)(xs[e] - (float)hh);
            }
            int kc  = aseg * 2 + (p >> 2);
            int oct = p & 3;
            int slot = ((kc * 4 + (arow >> 4)) * 64 + (oct << 4) + (arow & 15)) * 16;
            *(bf16x8*)(Alds + slot)              = hv;
            *(bf16x8*)(Alds + ALDS_SPLIT + slot) = lv;
        }
    }

    // ---- prologue: B fragments for iter 0 (ct=0, kc=0) ----
    bf16x8 B0h[4], B0l[4], B1h[4], B1l[4];
    {
        const char* pb  = cbP + ((size_t)wp * 8) * BBUF + bvoff;
        const char* pbl = pb + BPAN;
        #pragma unroll
        for (int j = 0; j < 4; ++j) {
            B0h[j] = *(const bf16x8*)(pb  + j * 1024);
            B0l[j] = *(const bf16x8*)(pbl + j * 1024);
        }
    }

    __syncthreads();   // A ready; the ONLY barrier before the reduction

    // ---- prologue: A fragments for iter 0 (kc=0) ----
    bf16x8 A0h[4], A0l[4], A1h[4], A1l[4];
    {
        const char* ab = Alds + (lane << 4);
        #pragma unroll
        for (int i = 0; i < 4; ++i) {
            A0h[i] = *(const bf16x8*)(ab + i * 1024);
            A0l[i] = *(const bf16x8*)(ab + ALDS_SPLIT + i * 1024);
        }
    }

    float cnj[4];

#define VQ_BODY(N, CAH, CAL, NAH, NAL, CBH, CBL, NBH, NBL)                    \
    {                                                                         \
        const int ct = (N) >> 3, kc = (N) & 7;                                \
        const int np = (N) + 1;                                               \
        if (np < NIT) {                                                       \
            const int ct1 = np >> 3, kc1 = np & 7;                            \
            const char* pb  = cbP                                             \
                + ((size_t)((ct1 * 2 + wp) * 8 + kc1)) * BBUF + bvoff;        \
            const char* pbl = pb + BPAN;                                      \
            _Pragma("unroll")                                                 \
            for (int j = 0; j < 4; ++j) {                                     \
                NBH[j] = *(const bf16x8*)(pb  + j * 1024);                    \
                NBL[j] = *(const bf16x8*)(pbl + j * 1024);                    \
            }                                                                 \
        }                                                                     \
        {                                                                     \
            const int kcn = np & 7;                                           \
            const char* ab = Alds + (kcn << 12) + (lane << 4);                \
            _Pragma("unroll")                                                 \
            for (int i = 0; i < 4; ++i) {                                     \
                NAH[i] = *(const bf16x8*)(ab + i * 1024);                     \
                NAL[i] = *(const bf16x8*)(ab + ALDS_SPLIT + i * 1024);        \
            }                                                                 \
        }                                                                     \
        if (kc == 0) {                                                        \
            _Pragma("unroll")                                                 \
            for (int j = 0; j < 4; ++j)                                       \
                cnj[j] = cnorm[(ct * 16 + wave * 4 + j) * 16 + l15];          \
        }                                                                     \
        __builtin_amdgcn_s_setprio(1);                                        \
        _Pragma("unroll")                                                     \
        for (int i = 0; i < 4; ++i)                                           \
            _Pragma("unroll")                                                 \
            for (int j = 0; j < 4; ++j)                                       \
                acc[i][j] = __builtin_amdgcn_mfma_f32_16x16x32_bf16(          \
                                CAH[i], CBH[j], acc[i][j], 0, 0, 0);          \
        _Pragma("unroll")                                                     \
        for (int i = 0; i < 4; ++i)                                           \
            _Pragma("unroll")                                                 \
            for (int j = 0; j < 4; ++j)                                       \
                acc[i][j] = __builtin_amdgcn_mfma_f32_16x16x32_bf16(          \
                                CAH[i], CBL[j], acc[i][j], 0, 0, 0);          \
        _Pragma("unroll")                                                     \
        for (int i = 0; i < 4; ++i)                                           \
            _Pragma("unroll")                                                 \
            for (int j = 0; j < 4; ++j)                                       \
                acc[i][j] = __builtin_amdgcn_mfma_f32_16x16x32_bf16(          \
                                CAL[i], CBH[j], acc[i][j], 0, 0, 0);          \
        __builtin_amdgcn_s_setprio(0);                                        \
        if (kc == 7) {                                                        \
            _Pragma("unroll")                                                 \
            for (int j = 0; j < 4; ++j) {                                     \
                int code = (ct * 16 + wave * 4 + j) * 16 + l15;               \
                float cn = cnj[j];                                            \
                _Pragma("unroll")                                             \
                for (int i = 0; i < 4; ++i) {                                 \
                    _Pragma("unroll")                                         \
                    for (int r = 0; r < 4; ++r) {                             \
                        float d = fmaf(-2.f, acc[i][j][r], cn);               \
                        int s = i * 4 + r;                                    \
                        if (d < mv[s]) { mv[s] = d; mi[s] = code; }           \
                    }                                                         \
                    acc[i][j] = (f32x4){0.f, 0.f, 0.f, 0.f};                  \
                }                                                             \
            }                                                                 \
        }                                                                     \
    }

    for (int n = 0; n < NIT; n += 2) {
        VQ_BODY(n,     A0h, A0l, A1h, A1l, B0h, B0l, B1h, B1l)
        VQ_BODY(n + 1, A1h, A1l, A0h, A0l, B1h, B1l, B0h, B0l)
    }
#undef VQ_BODY

    // ---- reduction: 16-lane butterfly (codes), then cross-wave via LDS ----
    #pragma unroll
    for (int s = 0; s < 16; ++s) {
        #pragma unroll
        for (int m = 1; m <= 8; m <<= 1) {
            float ov = __shfl_xor(mv[s], m, 64);
            int   oi = __shfl_xor(mi[s], m, 64);
            if (ov < mv[s] || (ov == mv[s] && oi < mi[s])) { mv[s] = ov; mi[s] = oi; }
        }
    }
    __syncthreads();
    float* redV  = (float*)Alds;                // [4 wave][64 rows]
    int*   redI  = (int*)(Alds + 4 * BM * 4);
    int*   bestI = (int*)(Alds + 8 * BM * 4);   // final per-row winner
    if (l15 == 0) {
        int qq = lane >> 4;
        #pragma unroll
        for (int i = 0; i < 4; ++i)
            #pragma unroll
            for (int r = 0; r < 4; ++r) {
                int ml = i * 16 + qq * 4 + r;
                redV[wave * BM + ml] = mv[i * 4 + r];
                redI[wave * BM + ml] = mi[i * 4 + r];
            }
    }
    __syncthreads();
    if (t < BM) {
        float bv = redV[t];
        int   bi = redI[t];
        #pragma unroll
        for (int w = 1; w < 4; ++w) {
            float v  = redV[w * BM + t];
            int   id = redI[w * BM + t];
            if (v < bv || (v == bv && id < bi)) { bv = v; bi = id; }
        }
        idx_out[row0 + t] = (float)bi;
        if (FUSE) bestI[t] = bi;
    }

    if (FUSE) {
        // ---- fused gather: block writes its own 64 quant rows ----
        __syncthreads();
        const int grow = t >> 2;
        const int gseg = t & 3;
        const int best = bestI[grow];
        const float4* src = (const float4*)cb + (size_t)best * (KDIM / 4);
        float4* dst = (float4*)quant + (size_t)(row0 + grow) * (KDIM / 4);
        #pragma unroll
        for (int i = 0; i < 16; ++i)
            dst[gseg * 16 + i] = src[gseg * 16 + i];
    }
}

// ---------------------------------------------------------------------------
// K4 (fallback only, panels in d_out): gather codebook rows into quantized
// output after K2 completes.
// ---------------------------------------------------------------------------
__global__ void vq_gather_kernel(const float* __restrict__ cb,
                                 const float* __restrict__ idx_f,
                                 float* __restrict__ quant) {
    const int t   = threadIdx.x;
    const int row = blockIdx.x * 64 + (t >> 2);
    const int seg = t & 3;
    const int best = (int)idx_f[row];
    const float4* src = (const float4*)cb + (size_t)best * (KDIM / 4);
    float4* dst = (float4*)quant + (size_t)row * (KDIM / 4);
    #pragma unroll
    for (int i = 0; i < 16; ++i)
        dst[seg * 16 + i] = src[seg * 16 + i];
}

// ---------------------------------------------------------------------------
extern "C" void kernel_launch(void* const* d_in, const int* in_sizes, int n_in,
                              void* d_out, int out_size, void* d_ws, size_t ws_size,
                              hipStream_t stream) {
    const float* z  = (const float*)d_in[0];
    const float* cb = (const float*)d_in[1];
    float* quant   = (float*)d_out;
    float* idx_out = (float*)d_out + QOUT_OFFSET;
    float* cnorm   = (float*)d_ws;                 // 32 KB scratch

    const bool fuse = ws_size >= (size_t)(32 * 1024) + PANEL_BYTES;
    char* cbP = fuse ? ((char*)d_ws + 32 * 1024)   // panels in workspace
                     : (char*)d_out;               // fallback: quant region

    vq_panel_kernel<<<NCODES / 64, 256, 0, stream>>>(cb, cbP, cnorm);
    if (fuse) {
        vq_main_kernel<1><<<NROWS / BM, THREADS, 0, stream>>>(
            z, cbP, cnorm, cb, quant, idx_out);
    } else {
        vq_main_kernel<0><<<NROWS / BM, THREADS, 0, stream>>>(
            z, cbP, cnorm, cb, quant, idx_out);
        vq_gather_kernel<<<NROWS / 64, 256, 0, stream>>>(cb, idx_out, quant);
    }
}